// Round 22
// baseline (213.612 us; speedup 1.0000x reference)
//
#include <hip/hip_runtime.h>
#include <math.h>

#define SEQ 4096
#define BATCH 8
#define NIN 1024
#define NH 256
#define NOUT 128
#define M (SEQ*BATCH)   // 32768
#define CHUNK 128
#define NCHUNK (SEQ/CHUNK)   // 32

typedef _Float16 half8 __attribute__((ext_vector_type(8)));
typedef float f32x4 __attribute__((ext_vector_type(4)));
union U4H8 { uint4 u; half8 h; };
union USH { unsigned short u; _Float16 h; };

__device__ __forceinline__ unsigned pkh2(float a, float b) {
    unsigned r;
    asm("v_cvt_pkrtz_f16_f32 %0, %1, %2" : "=v"(r) : "v"(a), "v"(b));
    return r;
}

// ---------------- K0: Wt[n][k] = (f16) W_xh[k][n] — one-shot transpose ----------
// 64 blocks (16 k-tiles x 4 n-tiles of 64x64), LDS f32 [64][65] (conflict-free).
__global__ __launch_bounds__(256) void k_wxt(const float* __restrict__ Wi2h,
                                             unsigned short* __restrict__ Wt) {
    __shared__ float Tl[64][65];
    int b = blockIdx.x;
    int k0 = (b & 15) * 64;
    int n0 = (b >> 4) * 64;
    int t = threadIdx.x;
    int c = t & 63;               // n offset (coalesced global read)
    int rg = t >> 6;              // 0..3
    #pragma unroll
    for (int rr = 0; rr < 16; rr++) {
        int r = rg * 16 + rr;
        Tl[c][r] = Wi2h[(size_t)(k0 + r) * NH + n0 + c];
    }
    __syncthreads();
    int n = t >> 2;               // 0..63
    int kq = t & 3;               // 0..3
    #pragma unroll
    for (int kk = 0; kk < 16; kk += 2) {
        int k = kq * 16 + kk;
        unsigned p = pkh2(Tl[n][k], Tl[n][k + 1]);
        *(unsigned*)&Wt[(size_t)(n0 + n) * NIN + k0 + k] = p;
    }
}

// ---------------- K1: xp16 = f16( x @ W_xh + b ) via MFMA, Wt-direct B ------------
// 256 blocks (128-row tiles), 1024 thr = 16 waves (4m x 4n), 4 waves/SIMD.
// R21 diagnosis: old K1 at 97us had MfmaUtil 6.4%, 3.67M LDS conflicts (W
// transpose-staging), 2 waves/SIMD, vmcnt-draining barriers. Fixes:
// (a) B-frags load DIRECTLY from pre-transposed f16 Wt (L2-resident 0.5MB) —
//     no W staging at all; (b) X-only LDS, double-buffered, ONE lgkm-only
//     barrier/iter; (c) next-chunk X+B prefetched into regs before MFMAs —
//     global loads stay in flight across the barrier; (d) 4 waves/SIMD TLP.
// Wave (wm,wn): A-tiles rows wm*32+{0,16}, B-tiles cols wn*64+{0..3}*16 ->
// 8 MFMA/iter, acc[2][4]. Fragment k-slot map (g,e)->k0+g*8+e for BOTH A and
// B (HW-validated R8/R14-21). Output written as f16 (xp16) — seeds the scan's
// f32 accumulator; quantization ~4e-4, same order as existing f16 h/W noise.
__global__ __launch_bounds__(1024) __attribute__((amdgpu_waves_per_eu(4, 4)))
void k_xproj(const float* __restrict__ x,
             const unsigned short* __restrict__ Wt,
             const float* __restrict__ bi2h,
             unsigned short* __restrict__ xp16) {
    __shared__ __align__(16) unsigned short Xl[2][128][40];
    int m0 = blockIdx.x * 128;
    int tid = threadIdx.x;
    int w = tid >> 6;
    int l = tid & 63;
    int col = l & 15;
    int g = l >> 4;
    int wm = w >> 2, wn = w & 3;
    int sr = tid >> 3;            // 0..127: X stage row
    int sk = tid & 7;             // 0..7:   X stage k-quad (4 f32)

    f32x4 acc[2][4];
    #pragma unroll
    for (int at = 0; at < 2; at++)
        #pragma unroll
        for (int bt = 0; bt < 4; bt++) {
            acc[at][bt][0] = 0.f; acc[at][bt][1] = 0.f;
            acc[at][bt][2] = 0.f; acc[at][bt][3] = 0.f;
        }

    // prologue: chunk 0 X -> LDS buf0, B0 -> regs
    uint4 bq[2][4];
    {
        float4 xv = *(const float4*)&x[(size_t)(m0 + sr) * NIN + sk*4];
        #pragma unroll
        for (int bt = 0; bt < 4; bt++)
            bq[0][bt] = *(const uint4*)&Wt[(size_t)(wn*64 + bt*16 + col) * NIN + g*8];
        uint2 xu; xu.x = pkh2(xv.x, xv.y); xu.y = pkh2(xv.z, xv.w);
        *(uint2*)&Xl[0][sr][sk*4] = xu;
    }
    asm volatile("s_waitcnt lgkmcnt(0)" ::: "memory");
    __builtin_amdgcn_s_barrier();
    asm volatile("" ::: "memory");

    #pragma unroll
    for (int i = 0; i < 32; i++) {
        int cur = i & 1, nxt = cur ^ 1;
        float4 xn;
        if (i < 31) {
            int k0 = (i + 1) * 32;
            xn = *(const float4*)&x[(size_t)(m0 + sr) * NIN + k0 + sk*4];
            #pragma unroll
            for (int bt = 0; bt < 4; bt++)
                bq[nxt][bt] = *(const uint4*)&Wt[(size_t)(wn*64 + bt*16 + col) * NIN + k0 + g*8];
        }
        U4H8 a0, a1;
        a0.u = *(const uint4*)&Xl[cur][wm*32 +      col][g*8];
        a1.u = *(const uint4*)&Xl[cur][wm*32 + 16 + col][g*8];
        #pragma unroll
        for (int bt = 0; bt < 4; bt++) {
            U4H8 bf; bf.u = bq[cur][bt];
            acc[0][bt] = __builtin_amdgcn_mfma_f32_16x16x32_f16(a0.h, bf.h, acc[0][bt], 0, 0, 0);
            acc[1][bt] = __builtin_amdgcn_mfma_f32_16x16x32_f16(a1.h, bf.h, acc[1][bt], 0, 0, 0);
        }
        if (i < 31) {
            uint2 xw; xw.x = pkh2(xn.x, xn.y); xw.y = pkh2(xn.z, xn.w);
            *(uint2*)&Xl[nxt][sr][sk*4] = xw;
        }
        asm volatile("s_waitcnt lgkmcnt(0)" ::: "memory");
        __builtin_amdgcn_s_barrier();
        asm volatile("" ::: "memory");
    }

    #pragma unroll
    for (int bt = 0; bt < 4; bt++) {
        float bias = bi2h[wn*64 + bt*16 + col];
        #pragma unroll
        for (int at = 0; at < 2; at++)
            #pragma unroll
            for (int q = 0; q < 4; q++) {
                USH v; v.h = (_Float16)(acc[at][bt][q] + bias);
                xp16[(size_t)(m0 + wm*32 + at*16 + g*4 + q) * NH + wn*64 + bt*16 + col] = v.u;
            }
    }
}

// ---------------- K2: CHUNKED 2-pass MFMA scan (R21, xp now f16) ------------------
// Contraction gamma^128 <= 2.3e-5: pass 1 runs each 128-step chunk from h=0
// (chunk 0: h0), writes only chunk-final h; pass 2 restarts from hs[t0-1] and
// writes the rest. Per-step body = R16 kernel (reproduced 4x).
template <int PASS>
__global__ __launch_bounds__(1024) __attribute__((amdgpu_waves_per_eu(4, 4)))
void k_scan_chunk(const float* __restrict__ Wi2h,
                  const float* __restrict__ h0,
                  const unsigned short* __restrict__ xp16,
                  float* __restrict__ hs) {
    __shared__ __align__(16) unsigned short hbuf[2][NH];
    int blk = blockIdx.x;
    int c = blk >> 3;
    int b = blk & 7;
    int t0 = c * CHUNK;
    int tend = t0 + CHUNK;
    int tid = threadIdx.x;
    int w = tid >> 6;
    int l = tid & 63;
    int col = l & 15;
    int g = l >> 4;
    int j = w*16 + col;

    uint4 wb[8];
    #pragma unroll
    for (int kt = 0; kt < 8; kt++) {
        int kbase = kt*32 + g*8;
        U4H8 f;
        #pragma unroll
        for (int e = 0; e < 8; e++)
            f.h[e] = (_Float16)Wi2h[(size_t)(NIN + kbase + e)*NH + j];
        wb[kt] = f.u;
    }
    #pragma unroll
    for (int kt = 0; kt < 8; kt++)
        asm volatile("" : "+v"(wb[kt].x), "+v"(wb[kt].y),
                         "+v"(wb[kt].z), "+v"(wb[kt].w));

    if (tid < NH) {
        float hv;
        if (c == 0)          hv = h0[b*NH + tid];
        else if (PASS == 1)  hv = 0.f;
        else                 hv = hs[((size_t)(t0 - 1)*BATCH + b)*NH + tid];
        _Float16 hf = (_Float16)hv;
        hbuf[0][tid] = __builtin_bit_cast(unsigned short, hf);
    }
    __syncthreads();

    USH x0; x0.u = xp16[((size_t)t0*BATCH + b)*NH + j];
    float xq = (float)x0.h;

    for (int t = t0; t < tend; t++) {
        int ts = t - t0;
        int cur = ts & 1, nxt = cur ^ 1;

        const char* hb = (const char*)&hbuf[cur][0];
        uint4 ha[8];
        #pragma unroll
        for (int kt = 0; kt < 8; kt++)
            ha[kt] = *(const uint4*)(hb + (kt*32 + g*8)*2);

        int tn = (t + 1 < tend) ? t + 1 : t;
        USH xr; xr.u = xp16[((size_t)tn*BATCH + b)*NH + j];
        float xn = (float)xr.h;

        f32x4 acc;
        acc[0] = xq; acc[1] = xq; acc[2] = xq; acc[3] = xq;
        #pragma unroll
        for (int kt = 0; kt < 8; kt++) {
            U4H8 av; av.u = ha[kt];
            U4H8 bv; bv.u = wb[kt];
            acc = __builtin_amdgcn_mfma_f32_16x16x32_f16(av.h, bv.h, acc, 0, 0, 0);
        }

        float s = acc[0];
        float arg = s * 2.88539004f;
        float z;   asm("v_exp_f32 %0, %1" : "=v"(z)   : "v"(arg));
        float den = z + 1.0f;
        float inv; asm("v_rcp_f32 %0, %1" : "=v"(inv) : "v"(den));
        float hn = (z - 1.0f) * inv;

        if (g == 0) {
            _Float16 hf = (_Float16)hn;
            hbuf[nxt][j] = __builtin_bit_cast(unsigned short, hf);
        } else if (g == 1) {
            bool wr = (PASS == 1) ? (t == tend - 1) : (t < tend - 1);
            if (wr) hs[((size_t)t*BATCH + b)*NH + j] = hn;
        }
        xq = xn;

        asm volatile("s_waitcnt lgkmcnt(0)" ::: "memory");
        __builtin_amdgcn_s_barrier();
        asm volatile("" ::: "memory");
    }
}

// ---------------- K3: out = hs @ W_h2o + b_h2o via f16 MFMA, 64x128 tile (R20) ----
__global__ __launch_bounds__(256) void k_out(const float* __restrict__ hs,
                                             const float* __restrict__ Wh2o,
                                             const float* __restrict__ bh2o,
                                             float* __restrict__ out) {
    __shared__ __align__(16) unsigned short Hl[64][40];
    __shared__ __align__(16) unsigned short Wl[128][40];
    int m0 = blockIdx.x * 64;
    int tid = threadIdx.x;
    int w = tid >> 6;
    int l = tid & 63;
    int col = l & 15;
    int g = l >> 4;

    int sr = tid >> 2;
    int sk = tid & 3;
    int sn = tid & 127;
    int sg = tid >> 7;

    f32x4 acc[8];
    #pragma unroll
    for (int bt = 0; bt < 8; bt++) {
        acc[bt][0] = 0.f; acc[bt][1] = 0.f; acc[bt][2] = 0.f; acc[bt][3] = 0.f;
    }

    for (int k0 = 0; k0 < NH; k0 += 32) {
        float4 xa = *(const float4*)&hs[(size_t)(m0 + sr) * NH + k0 + sk*8];
        float4 xb = *(const float4*)&hs[(size_t)(m0 + sr) * NH + k0 + sk*8 + 4];
        float wv[16];
        #pragma unroll
        for (int jq = 0; jq < 4; jq++)
            #pragma unroll
            for (int p = 0; p < 4; p++)
                wv[jq*4 + p] = Wh2o[(size_t)(k0 + sg*16 + jq*4 + p) * NOUT + sn];
        __syncthreads();
        uint4 xu;
        xu.x = pkh2(xa.x, xa.y); xu.y = pkh2(xa.z, xa.w);
        xu.z = pkh2(xb.x, xb.y); xu.w = pkh2(xb.z, xb.w);
        *(uint4*)&Hl[sr][sk*8] = xu;
        #pragma unroll
        for (int jq = 0; jq < 4; jq++) {
            uint2 wu;
            wu.x = pkh2(wv[jq*4+0], wv[jq*4+1]);
            wu.y = pkh2(wv[jq*4+2], wv[jq*4+3]);
            *(uint2*)&Wl[sn][sg*16 + jq*4] = wu;
        }
        __syncthreads();
        U4H8 af; af.u = *(const uint4*)&Hl[w*16 + col][g*8];
        #pragma unroll
        for (int bt = 0; bt < 8; bt++) {
            U4H8 bf; bf.u = *(const uint4*)&Wl[bt*16 + col][g*8];
            acc[bt] = __builtin_amdgcn_mfma_f32_16x16x32_f16(af.h, bf.h, acc[bt], 0, 0, 0);
        }
    }

    #pragma unroll
    for (int bt = 0; bt < 8; bt++) {
        float bias = bh2o[bt*16 + col];
        #pragma unroll
        for (int q = 0; q < 4; q++)
            out[(size_t)(m0 + w*16 + g*4 + q) * NOUT + bt*16 + col] = acc[bt][q] + bias;
    }
}

extern "C" void kernel_launch(void* const* d_in, const int* in_sizes, int n_in,
                              void* d_out, int out_size, void* d_ws, size_t ws_size,
                              hipStream_t stream) {
    const float* x    = (const float*)d_in[0];
    const float* h0   = (const float*)d_in[1];
    const float* Wi2h = (const float*)d_in[2];
    const float* bi2h = (const float*)d_in[3];
    const float* Wh2o = (const float*)d_in[4];
    const float* bh2o = (const float*)d_in[5];
    float* out = (float*)d_out;

    unsigned short* xp16 = (unsigned short*)d_ws;                  // 16 MB
    float* hs = (float*)(xp16 + (size_t)M * NH);                   // 32 MB
    unsigned short* Wt = (unsigned short*)(hs + (size_t)M * NH);   // 0.5 MB

    k_wxt  <<<dim3(64),  dim3(256),  0, stream>>>(Wi2h, Wt);
    k_xproj<<<dim3(256), dim3(1024), 0, stream>>>(x, Wt, bi2h, xp16);
    k_scan_chunk<1><<<dim3(NCHUNK*BATCH), dim3(1024), 0, stream>>>(Wi2h, h0, xp16, hs);
    k_scan_chunk<2><<<dim3(NCHUNK*BATCH), dim3(1024), 0, stream>>>(Wi2h, h0, xp16, hs);
    k_out  <<<dim3(512), dim3(256),  0, stream>>>(hs, Wh2o, bh2o, out);
}

// Round 23
// 196.366 us; speedup vs baseline: 1.0878x; 1.0878x over previous
//
#include <hip/hip_runtime.h>
#include <math.h>

#define SEQ 4096
#define BATCH 8
#define NIN 1024
#define NH 256
#define NOUT 128
#define M (SEQ*BATCH)   // 32768
#define CHUNK 128
#define NCHUNK (SEQ/CHUNK)   // 32

typedef _Float16 half8 __attribute__((ext_vector_type(8)));
typedef float f32x4 __attribute__((ext_vector_type(4)));
union U4H8 { uint4 u; half8 h; };
union USH { unsigned short u; _Float16 h; };

__device__ __forceinline__ unsigned pkh2(float a, float b) {
    unsigned r;
    asm("v_cvt_pkrtz_f16_f32 %0, %1, %2" : "=v"(r) : "v"(a), "v"(b));
    return r;
}

// ---------------- K0: Wt[n][k] = (f16) W_xh[k][n] — one-shot transpose (R22) ------
__global__ __launch_bounds__(256) void k_wxt(const float* __restrict__ Wi2h,
                                             unsigned short* __restrict__ Wt) {
    __shared__ float Tl[64][65];
    int b = blockIdx.x;
    int k0 = (b & 15) * 64;
    int n0 = (b >> 4) * 64;
    int t = threadIdx.x;
    int c = t & 63;
    int rg = t >> 6;
    #pragma unroll
    for (int rr = 0; rr < 16; rr++) {
        int r = rg * 16 + rr;
        Tl[c][r] = Wi2h[(size_t)(k0 + r) * NH + n0 + c];
    }
    __syncthreads();
    int n = t >> 2;
    int kq = t & 3;
    #pragma unroll
    for (int kk = 0; kk < 16; kk += 2) {
        int k = kq * 16 + kk;
        unsigned p = pkh2(Tl[n][k], Tl[n][k + 1]);
        *(unsigned*)&Wt[(size_t)(n0 + n) * NIN + k0 + k] = p;
    }
}

// ---------------- K1: xp16 = f16( x @ W_xh + b ) — 512 thr, Wt-direct B ----------
// R22 failure: 1024-thr blocks get a ~56-VGPR allocator target (R12/R16/R22
// pattern) -> bq/staging spilled to scratch -> 100 us. 512-thr + wpe(2,2) is
// the proven shape (88-92 VGPR, no spill: R19-R21). Keeps R22's good parts:
// B-frags DIRECT from pre-transposed f16 Wt (L2-resident, no W staging);
// X-only double-buffered LDS; ONE lgkm-only barrier/iter; next-iter X + B
// prefetched into regs before the MFMAs (loads in flight across the barrier).
// 256 blocks (1/CU), 8 waves = 2m x 4n; wave = 4 A-tiles x 4 B-tiles ->
// 16 MFMA/iter, acc[4][4] in AGPRs. Fragment maps HW-validated (R8/R14-22).
__global__ __launch_bounds__(512) __attribute__((amdgpu_waves_per_eu(2, 2)))
void k_xproj(const float* __restrict__ x,
             const unsigned short* __restrict__ Wt,
             const float* __restrict__ bi2h,
             unsigned short* __restrict__ xp16) {
    __shared__ __align__(16) unsigned short Xl[2][128][40];
    int m0 = blockIdx.x * 128;
    int tid = threadIdx.x;
    int w = tid >> 6;
    int l = tid & 63;
    int col = l & 15;
    int g = l >> 4;
    int wm = w >> 2, wn = w & 3;
    int sr = tid >> 2;            // 0..127: X stage row
    int sk = tid & 3;             // 0..3:   X stage k-octet (8 f32)

    f32x4 acc[4][4];
    #pragma unroll
    for (int at = 0; at < 4; at++)
        #pragma unroll
        for (int bt = 0; bt < 4; bt++) {
            acc[at][bt][0] = 0.f; acc[at][bt][1] = 0.f;
            acc[at][bt][2] = 0.f; acc[at][bt][3] = 0.f;
        }

    // prologue: chunk 0 X -> LDS buf0, B0 -> regs
    uint4 bq[2][4];
    {
        float4 xa = *(const float4*)&x[(size_t)(m0 + sr) * NIN + sk*8];
        float4 xb = *(const float4*)&x[(size_t)(m0 + sr) * NIN + sk*8 + 4];
        #pragma unroll
        for (int bt = 0; bt < 4; bt++)
            bq[0][bt] = *(const uint4*)&Wt[(size_t)(wn*64 + bt*16 + col) * NIN + g*8];
        uint4 xu;
        xu.x = pkh2(xa.x, xa.y); xu.y = pkh2(xa.z, xa.w);
        xu.z = pkh2(xb.x, xb.y); xu.w = pkh2(xb.z, xb.w);
        *(uint4*)&Xl[0][sr][sk*8] = xu;
    }
    asm volatile("s_waitcnt lgkmcnt(0)" ::: "memory");
    __builtin_amdgcn_s_barrier();
    asm volatile("" ::: "memory");

    #pragma unroll
    for (int i = 0; i < 32; i++) {
        int cur = i & 1, nxt = cur ^ 1;
        float4 xa, xb;
        if (i < 31) {
            int k0 = (i + 1) * 32;
            xa = *(const float4*)&x[(size_t)(m0 + sr) * NIN + k0 + sk*8];
            xb = *(const float4*)&x[(size_t)(m0 + sr) * NIN + k0 + sk*8 + 4];
            #pragma unroll
            for (int bt = 0; bt < 4; bt++)
                bq[nxt][bt] = *(const uint4*)&Wt[(size_t)(wn*64 + bt*16 + col) * NIN + k0 + g*8];
        }
        U4H8 af[4];
        #pragma unroll
        for (int at = 0; at < 4; at++)
            af[at].u = *(const uint4*)&Xl[cur][wm*64 + at*16 + col][g*8];
        #pragma unroll
        for (int bt = 0; bt < 4; bt++) {
            U4H8 bf; bf.u = bq[cur][bt];
            #pragma unroll
            for (int at = 0; at < 4; at++)
                acc[at][bt] = __builtin_amdgcn_mfma_f32_16x16x32_f16(af[at].h, bf.h, acc[at][bt], 0, 0, 0);
        }
        if (i < 31) {
            uint4 xu;
            xu.x = pkh2(xa.x, xa.y); xu.y = pkh2(xa.z, xa.w);
            xu.z = pkh2(xb.x, xb.y); xu.w = pkh2(xb.z, xb.w);
            *(uint4*)&Xl[nxt][sr][sk*8] = xu;
        }
        asm volatile("s_waitcnt lgkmcnt(0)" ::: "memory");
        __builtin_amdgcn_s_barrier();
        asm volatile("" ::: "memory");
    }

    #pragma unroll
    for (int bt = 0; bt < 4; bt++) {
        float bias = bi2h[wn*64 + bt*16 + col];
        #pragma unroll
        for (int at = 0; at < 4; at++)
            #pragma unroll
            for (int q = 0; q < 4; q++) {
                USH v; v.h = (_Float16)(acc[at][bt][q] + bias);
                xp16[(size_t)(m0 + wm*64 + at*16 + g*4 + q) * NH + wn*64 + bt*16 + col] = v.u;
            }
    }
}

// ---------------- K2: CHUNKED 2-pass MFMA scan, hs stored f16 ---------------------
// Contraction gamma^128 <= 2.3e-5 (R21-validated: absmax unchanged).
// hs now f16: ZERO precision cost — h already lives as f16 in LDS; the stored
// value is bit-identical to the in-LDS one. Halves scan writes + K3 reads.
template <int PASS>
__global__ __launch_bounds__(1024) __attribute__((amdgpu_waves_per_eu(4, 4)))
void k_scan_chunk(const float* __restrict__ Wi2h,
                  const float* __restrict__ h0,
                  const unsigned short* __restrict__ xp16,
                  unsigned short* __restrict__ hs16) {
    __shared__ __align__(16) unsigned short hbuf[2][NH];
    int blk = blockIdx.x;
    int c = blk >> 3;
    int b = blk & 7;
    int t0 = c * CHUNK;
    int tend = t0 + CHUNK;
    int tid = threadIdx.x;
    int w = tid >> 6;
    int l = tid & 63;
    int col = l & 15;
    int g = l >> 4;
    int j = w*16 + col;

    uint4 wb[8];
    #pragma unroll
    for (int kt = 0; kt < 8; kt++) {
        int kbase = kt*32 + g*8;
        U4H8 f;
        #pragma unroll
        for (int e = 0; e < 8; e++)
            f.h[e] = (_Float16)Wi2h[(size_t)(NIN + kbase + e)*NH + j];
        wb[kt] = f.u;
    }
    #pragma unroll
    for (int kt = 0; kt < 8; kt++)
        asm volatile("" : "+v"(wb[kt].x), "+v"(wb[kt].y),
                         "+v"(wb[kt].z), "+v"(wb[kt].w));

    if (tid < NH) {
        USH hv;
        if (c == 0) {
            hv.h = (_Float16)h0[b*NH + tid];
        } else if (PASS == 1) {
            hv.h = (_Float16)0.f;
        } else {
            hv.u = hs16[((size_t)(t0 - 1)*BATCH + b)*NH + tid];
        }
        hbuf[0][tid] = hv.u;
    }
    __syncthreads();

    USH x0; x0.u = xp16[((size_t)t0*BATCH + b)*NH + j];
    float xq = (float)x0.h;

    for (int t = t0; t < tend; t++) {
        int ts = t - t0;
        int cur = ts & 1, nxt = cur ^ 1;

        const char* hb = (const char*)&hbuf[cur][0];
        uint4 ha[8];
        #pragma unroll
        for (int kt = 0; kt < 8; kt++)
            ha[kt] = *(const uint4*)(hb + (kt*32 + g*8)*2);

        int tn = (t + 1 < tend) ? t + 1 : t;
        USH xr; xr.u = xp16[((size_t)tn*BATCH + b)*NH + j];
        float xn = (float)xr.h;

        f32x4 acc;
        acc[0] = xq; acc[1] = xq; acc[2] = xq; acc[3] = xq;
        #pragma unroll
        for (int kt = 0; kt < 8; kt++) {
            U4H8 av; av.u = ha[kt];
            U4H8 bv; bv.u = wb[kt];
            acc = __builtin_amdgcn_mfma_f32_16x16x32_f16(av.h, bv.h, acc, 0, 0, 0);
        }

        float s = acc[0];
        float arg = s * 2.88539004f;
        float z;   asm("v_exp_f32 %0, %1" : "=v"(z)   : "v"(arg));
        float den = z + 1.0f;
        float inv; asm("v_rcp_f32 %0, %1" : "=v"(inv) : "v"(den));
        float hn = (z - 1.0f) * inv;

        USH hf; hf.h = (_Float16)hn;
        if (g == 0) {
            hbuf[nxt][j] = hf.u;
        } else if (g == 1) {
            bool wr = (PASS == 1) ? (t == tend - 1) : (t < tend - 1);
            if (wr) hs16[((size_t)t*BATCH + b)*NH + j] = hf.u;
        }
        xq = xn;

        asm volatile("s_waitcnt lgkmcnt(0)" ::: "memory");
        __builtin_amdgcn_s_barrier();
        asm volatile("" ::: "memory");
    }
}

// ---------------- K3: out = hs16 @ W_h2o + b_h2o via f16 MFMA ---------------------
// hs is f16 now: H staging is a pure uint4 copy (no cvt). 512 blocks, 256 thr.
__global__ __launch_bounds__(256) void k_out(const unsigned short* __restrict__ hs16,
                                             const float* __restrict__ Wh2o,
                                             const float* __restrict__ bh2o,
                                             float* __restrict__ out) {
    __shared__ __align__(16) unsigned short Hl[64][40];
    __shared__ __align__(16) unsigned short Wl[128][40];
    int m0 = blockIdx.x * 64;
    int tid = threadIdx.x;
    int w = tid >> 6;
    int l = tid & 63;
    int col = l & 15;
    int g = l >> 4;

    int sr = tid >> 2;            // 0..63: H row
    int sk = tid & 3;             // 0..3:  H k-octet (8 f16)
    int sn = tid & 127;           // 0..127: W col
    int sg = tid >> 7;            // 0..1:   W k-half (16 k)

    f32x4 acc[8];
    #pragma unroll
    for (int bt = 0; bt < 8; bt++) {
        acc[bt][0] = 0.f; acc[bt][1] = 0.f; acc[bt][2] = 0.f; acc[bt][3] = 0.f;
    }

    for (int k0 = 0; k0 < NH; k0 += 32) {
        uint4 hv4 = *(const uint4*)&hs16[(size_t)(m0 + sr) * NH + k0 + sk*8];
        float wv[16];
        #pragma unroll
        for (int jq = 0; jq < 4; jq++)
            #pragma unroll
            for (int p = 0; p < 4; p++)
                wv[jq*4 + p] = Wh2o[(size_t)(k0 + sg*16 + jq*4 + p) * NOUT + sn];
        __syncthreads();
        *(uint4*)&Hl[sr][sk*8] = hv4;
        #pragma unroll
        for (int jq = 0; jq < 4; jq++) {
            uint2 wu;
            wu.x = pkh2(wv[jq*4+0], wv[jq*4+1]);
            wu.y = pkh2(wv[jq*4+2], wv[jq*4+3]);
            *(uint2*)&Wl[sn][sg*16 + jq*4] = wu;
        }
        __syncthreads();
        U4H8 af; af.u = *(const uint4*)&Hl[w*16 + col][g*8];
        #pragma unroll
        for (int bt = 0; bt < 8; bt++) {
            U4H8 bf; bf.u = *(const uint4*)&Wl[bt*16 + col][g*8];
            acc[bt] = __builtin_amdgcn_mfma_f32_16x16x32_f16(af.h, bf.h, acc[bt], 0, 0, 0);
        }
    }

    #pragma unroll
    for (int bt = 0; bt < 8; bt++) {
        float bias = bh2o[bt*16 + col];
        #pragma unroll
        for (int q = 0; q < 4; q++)
            out[(size_t)(m0 + w*16 + g*4 + q) * NOUT + bt*16 + col] = acc[bt][q] + bias;
    }
}

extern "C" void kernel_launch(void* const* d_in, const int* in_sizes, int n_in,
                              void* d_out, int out_size, void* d_ws, size_t ws_size,
                              hipStream_t stream) {
    const float* x    = (const float*)d_in[0];
    const float* h0   = (const float*)d_in[1];
    const float* Wi2h = (const float*)d_in[2];
    const float* bi2h = (const float*)d_in[3];
    const float* Wh2o = (const float*)d_in[4];
    const float* bh2o = (const float*)d_in[5];
    float* out = (float*)d_out;

    unsigned short* xp16 = (unsigned short*)d_ws;                      // 16 MB
    unsigned short* hs16 = xp16 + (size_t)M * NH;                      // 16 MB
    unsigned short* Wt   = hs16 + (size_t)M * NH;                      // 0.5 MB

    k_wxt  <<<dim3(64),  dim3(256), 0, stream>>>(Wi2h, Wt);
    k_xproj<<<dim3(256), dim3(512), 0, stream>>>(x, Wt, bi2h, xp16);
    k_scan_chunk<1><<<dim3(NCHUNK*BATCH), dim3(1024), 0, stream>>>(Wi2h, h0, xp16, hs16);
    k_scan_chunk<2><<<dim3(NCHUNK*BATCH), dim3(1024), 0, stream>>>(Wi2h, h0, xp16, hs16);
    k_out  <<<dim3(512), dim3(256), 0, stream>>>(hs16, Wh2o, bh2o, out);
}